// Round 1
// baseline (272.599 us; speedup 1.0000x reference)
//
#include <hip/hip_runtime.h>

#define N_NODES 50000
#define DIM 128
#define N_EDGES 625000
#define NBLK 196   // ceil(N/256) scan blocks
#define EBLK 2442  // ceil(E/256) edge blocks

// k_setup grid partition
#define SC_BLOCKS 12500           // scales/tangents: 16 rows/block over 4N rows
#define PK_BLOCKS 256             // W-pack: 65536 elems
#define ZR_BLOCKS 391             // zero deg+cursor: 100,000 ints
#define SETUP_BLOCKS (SC_BLOCKS + PK_BLOCKS + ZR_BLOCKS)

typedef float f32x4 __attribute__((ext_vector_type(4)));
typedef short s16x8 __attribute__((ext_vector_type(8)));

union U8 { unsigned short us[8]; uint4 v; };

__device__ __forceinline__ unsigned short f2bf(float f) {
    unsigned u = __builtin_bit_cast(unsigned, f);
    unsigned r = (u + 0x7fffu + ((u >> 16) & 1u)) >> 16;  // RNE
    return (unsigned short)r;
}
__device__ __forceinline__ float lo_bf(unsigned u) {
    return __builtin_bit_cast(float, u << 16);
}
__device__ __forceinline__ float hi_bf(unsigned u) {
    return __builtin_bit_cast(float, u & 0xffff0000u);
}

// async global->LDS, 16 B per lane; lds dest = uniform base + lane*16 (m104)
__device__ __forceinline__ void gload_lds16(const unsigned short* g, unsigned short* l) {
    __builtin_amdgcn_global_load_lds(
        (const __attribute__((address_space(1))) void*)g,
        (__attribute__((address_space(3))) void*)l, 16, 0, 0);
}

// ---- K1 fused setup ----
// blocks [0, SC): logmap0 per-row scale; a==0 -> node_t = bf16(scale*node);
//                 a>0 -> A[n][a*128..] = bf16(scale*h_a)  (pre-packed GEMM A cols)
// blocks [SC, SC+PK): pack Wt[o][k] bf16 (k<128: lin_w[o][k]; else conv_w[o][i][kk])
// blocks [SC+PK, ...): zero deg+cursor
__global__ __launch_bounds__(256) void k_setup(
    const float* __restrict__ node, const float* __restrict__ h1,
    const float* __restrict__ h2, const float* __restrict__ h3,
    const float* __restrict__ lin_w, const float* __restrict__ conv_w,
    const float* __restrict__ curv,
    unsigned short* __restrict__ node_t, unsigned short* __restrict__ A,
    unsigned short* __restrict__ Wt, int* __restrict__ zero_base) {
    int b = blockIdx.x;
    int tid = threadIdx.x;
    if (b < SC_BLOCKS) {
        int row = b * 16 + (tid >> 4);  // [0, 4N); matrix index uniform per block
        int g = tid & 15;
        int a = row / N_NODES;
        int n = row - a * N_NODES;
        const float* src = (a == 0) ? node : (a == 1) ? h1 : (a == 2) ? h2 : h3;
        const float4* p = (const float4*)&src[n * DIM + g * 8];
        float4 x0 = p[0], x1 = p[1];
        float ss = x0.x * x0.x + x0.y * x0.y + x0.z * x0.z + x0.w * x0.w
                 + x1.x * x1.x + x1.y * x1.y + x1.z * x1.z + x1.w * x1.w;
        ss += __shfl_xor(ss, 1, 64);
        ss += __shfl_xor(ss, 2, 64);
        ss += __shfl_xor(ss, 4, 64);
        ss += __shfl_xor(ss, 8, 64);  // 16-lane group reduction
        float c = fabsf(curv[0]);
        float sc = sqrtf(c);
        float xn = fmaxf(sqrtf(ss), 1e-15f);
        float arg = fminf(sc * xn, 1.0f - 1e-5f);
        // s = artanh(arg)/(sc*xn). When arg<0.25 clipping is inactive so
        // arg == sc*xn and the division cancels: s = artanh(z)/z poly.
        // Series error at z=0.25 ~1.7e-6 rel, far below bf16 rounding.
        float s;
        if (arg < 0.25f) {
            float z2 = arg * arg;
            s = 1.0f + z2 * (0.33333333f + z2 * (0.2f + z2 * 0.14285715f));
        } else {
            float at = 0.5f * log1pf(2.0f * arg / (1.0f - arg));  // artanh
            s = at / (sc * xn);
        }
        U8 u;
        u.us[0] = f2bf(x0.x * s); u.us[1] = f2bf(x0.y * s);
        u.us[2] = f2bf(x0.z * s); u.us[3] = f2bf(x0.w * s);
        u.us[4] = f2bf(x1.x * s); u.us[5] = f2bf(x1.y * s);
        u.us[6] = f2bf(x1.z * s); u.us[7] = f2bf(x1.w * s);
        if (a == 0) {  // branch uniform per block
            *(uint4*)&node_t[n * DIM + g * 8] = u.v;
        } else {
            *(uint4*)&A[n * 512 + a * 128 + g * 8] = u.v;
        }
    } else if (b < SC_BLOCKS + PK_BLOCKS) {
        int idx = (b - SC_BLOCKS) * 256 + tid;  // 65536
        int o = idx >> 9;
        int k = idx & 511;
        float v;
        if (k < 128) {
            v = lin_w[o * 128 + k];
        } else {
            int kk = (k - 128) >> 7;
            int i = (k - 128) & 127;
            v = conv_w[o * 384 + i * 3 + kk];
        }
        Wt[idx] = f2bf(v);
    } else {
        int i = (b - SC_BLOCKS - PK_BLOCKS) * 256 + tid;
        if (i < 100000) zero_base[i] = 0;  // deg[50k] + cursor[50k], adjacent
    }
}

// ---- K2: degree histogram ----
__global__ void k_hist(const int* __restrict__ edst, int* __restrict__ deg) {
    int e = blockIdx.x * 256 + threadIdx.x;
    if (e < N_EDGES)
        __hip_atomic_fetch_add(&deg[edst[e]], 1, __ATOMIC_RELAXED, __HIP_MEMORY_SCOPE_AGENT);
}

// ---- K3a: per-256-chunk exclusive scan; chunk totals -> blocksum ----
__global__ void k_scan1(const int* __restrict__ deg, int* __restrict__ rowstart,
                        int* __restrict__ blocksum) {
    __shared__ int sm[256];
    int t = threadIdx.x;
    int i = blockIdx.x * 256 + t;
    int v = (i < N_NODES) ? deg[i] : 0;
    sm[t] = v;
    __syncthreads();
    #pragma unroll
    for (int off = 1; off < 256; off <<= 1) {
        int x = (t >= off) ? sm[t - off] : 0;
        __syncthreads();
        sm[t] += x;
        __syncthreads();
    }
    if (i < N_NODES) rowstart[i] = sm[t] - v;  // exclusive within chunk
    if (t == 255) blocksum[blockIdx.x] = sm[t];
}

// ---- K3b: exclusive scan of chunk totals (in place) ----
__global__ void k_scan2(int* __restrict__ blocksum) {
    __shared__ int sm[256];
    int t = threadIdx.x;
    int v = (t < NBLK) ? blocksum[t] : 0;
    sm[t] = v;
    __syncthreads();
    #pragma unroll
    for (int off = 1; off < 256; off <<= 1) {
        int x = (t >= off) ? sm[t - off] : 0;
        __syncthreads();
        sm[t] += x;
        __syncthreads();
    }
    if (t < NBLK) blocksum[t] = sm[t] - v;  // exclusive
}

// ---- K4: bucket edge sources by destination (CSR fill) ----
__global__ void k_bucket(const int* __restrict__ esrc, const int* __restrict__ edst,
                         const int* __restrict__ rowstart, const int* __restrict__ blocksum,
                         int* __restrict__ cursor, int* __restrict__ csr_src) {
    int e = blockIdx.x * 256 + threadIdx.x;
    if (e >= N_EDGES) return;
    int d = edst[e];
    int pos = __hip_atomic_fetch_add(&cursor[d], 1, __ATOMIC_RELAXED, __HIP_MEMORY_SCOPE_AGENT);
    csr_src[rowstart[d] + blocksum[d >> 8] + pos] = esrc[e];
}

// ---- K5: gather: A[n][0:128] = bf16(avg of node_t rows in CSR row n) ----
__global__ __launch_bounds__(256) void k_gather(
    const int* __restrict__ csr_src, const int* __restrict__ rowstart,
    const int* __restrict__ blocksum, const int* __restrict__ deg,
    const unsigned short* __restrict__ node_t, unsigned short* __restrict__ A) {
    int n = blockIdx.x * 4 + (threadIdx.x >> 6);
    int lane = threadIdx.x & 63;
    int begin = rowstart[n] + blocksum[n >> 8];
    int cnt = deg[n];
    float a0 = 0.f, a1 = 0.f, b0 = 0.f, b1 = 0.f;
    float c0 = 0.f, c1 = 0.f, d0 = 0.f, d1 = 0.f;
    for (int base = 0; base < cnt; base += 64) {
        int rem = cnt - base;
        int m = rem < 64 ? rem : 64;
        int my = (lane < m) ? csr_src[begin + base + lane] : 0;
        int i = 0;
        for (; i + 8 <= m; i += 8) {
            int s0 = __shfl(my, i, 64),     s1 = __shfl(my, i + 1, 64);
            int s2 = __shfl(my, i + 2, 64), s3 = __shfl(my, i + 3, 64);
            int s4 = __shfl(my, i + 4, 64), s5 = __shfl(my, i + 5, 64);
            int s6 = __shfl(my, i + 6, 64), s7 = __shfl(my, i + 7, 64);
            unsigned u0 = *(const unsigned*)&node_t[s0 * DIM + lane * 2];
            unsigned u1 = *(const unsigned*)&node_t[s1 * DIM + lane * 2];
            unsigned u2 = *(const unsigned*)&node_t[s2 * DIM + lane * 2];
            unsigned u3 = *(const unsigned*)&node_t[s3 * DIM + lane * 2];
            unsigned u4 = *(const unsigned*)&node_t[s4 * DIM + lane * 2];
            unsigned u5 = *(const unsigned*)&node_t[s5 * DIM + lane * 2];
            unsigned u6 = *(const unsigned*)&node_t[s6 * DIM + lane * 2];
            unsigned u7 = *(const unsigned*)&node_t[s7 * DIM + lane * 2];
            a0 += lo_bf(u0); a1 += hi_bf(u0);
            b0 += lo_bf(u1); b1 += hi_bf(u1);
            c0 += lo_bf(u2); c1 += hi_bf(u2);
            d0 += lo_bf(u3); d1 += hi_bf(u3);
            a0 += lo_bf(u4); a1 += hi_bf(u4);
            b0 += lo_bf(u5); b1 += hi_bf(u5);
            c0 += lo_bf(u6); c1 += hi_bf(u6);
            d0 += lo_bf(u7); d1 += hi_bf(u7);
        }
        for (; i < m; ++i) {
            int s = __shfl(my, i, 64);
            unsigned u = *(const unsigned*)&node_t[s * DIM + lane * 2];
            a0 += lo_bf(u); a1 += hi_bf(u);
        }
    }
    float t0 = (a0 + b0) + (c0 + d0);
    float t1 = (a1 + b1) + (c1 + d1);
    float inv = (cnt > 0) ? 1.0f / (float)cnt : 0.0f;
    unsigned short o0 = f2bf(t0 * inv), o1 = f2bf(t1 * inv);
    *(unsigned*)&A[n * 512 + lane * 2] = (unsigned)o0 | ((unsigned)o1 << 16);
}

// ---- K6: [N x 512] @ [512 x 128] bf16 MFMA GEMM + expmap0 epilogue (f32 out) ----
// v2: BK=64 double-buffered 2-phase pipeline (guide T3 minimum template):
//   prologue STAGE(0,buf0); per chunk: {barrier (drains own vmcnt);
//   issue STAGE(k+1, other buf); ds_read+MFMA on current buf}.
// Prefetch latency hides under the previous chunk's compute; one barrier/chunk.
// LDS 2*(8+16) KB = 48 KB -> 3 blocks/CU. XOR swizzle: 16-B chunk j of row r
// lives at slot j^(r&7) within the 128-B row (involution on both sides).
#define RB 64
#define BK 64
__global__ __launch_bounds__(256) void k_gemm(
    const unsigned short* __restrict__ A, const int* __restrict__ deg,
    const unsigned short* __restrict__ Wt,  // [128][512] bf16
    const float* __restrict__ lin_b, const float* __restrict__ conv_b,
    const float* __restrict__ curv, float* __restrict__ out) {
    __shared__ __align__(16) unsigned short As[2][RB * BK];    // 8 KB each
    __shared__ __align__(16) unsigned short Bs[2][128 * BK];   // 16 KB each
    int tid = threadIdx.x;
    int n0 = blockIdx.x * RB;
    int w = tid >> 6;
    int lane = tid & 63;
    int ml = lane & 15;
    int q = lane >> 4;
    int lr = lane >> 3;      // row-within-8 for staging
    int lj = lane & 7;       // 16B-chunk-within-row for staging

    f32x4 acc[8];
    #pragma unroll
    for (int i = 0; i < 8; ++i) acc[i] = (f32x4){0.f, 0.f, 0.f, 0.f};

    // prologue: stage chunk 0 into buffer 0
    #pragma unroll
    for (int t = 0; t < 2; ++t) {
        int m = t * 4 + w;
        int r = m * 8 + lr;
        int jg = lj ^ (r & 7);
        gload_lds16(A + (n0 + r) * 512 + jg * 8, &As[0][m * 512]);
    }
    #pragma unroll
    for (int t = 0; t < 4; ++t) {
        int m = t * 4 + w;
        int r = m * 8 + lr;
        int jg = lj ^ (r & 7);
        gload_lds16(Wt + r * 512 + jg * 8, &Bs[0][m * 512]);
    }

    #pragma unroll
    for (int kk = 0; kk < 8; ++kk) {
        int cur = kk & 1;
        // drains own vmcnt (stage kk) + lgkmcnt, then barrier: after this,
        // ALL waves' stage-kk loads have landed and all waves finished
        // computing from the other buffer -> safe to overwrite it.
        __syncthreads();
        if (kk < 7) {
            int nb = cur ^ 1;
            #pragma unroll
            for (int t = 0; t < 2; ++t) {
                int m = t * 4 + w;
                int r = m * 8 + lr;
                int jg = lj ^ (r & 7);
                gload_lds16(A + (n0 + r) * 512 + (kk + 1) * 64 + jg * 8, &As[nb][m * 512]);
            }
            #pragma unroll
            for (int t = 0; t < 4; ++t) {
                int m = t * 4 + w;
                int r = m * 8 + lr;
                int jg = lj ^ (r & 7);
                gload_lds16(Wt + r * 512 + (kk + 1) * 64 + jg * 8, &Bs[nb][m * 512]);
            }
        }
        __builtin_amdgcn_s_setprio(1);
        #pragma unroll
        for (int ks = 0; ks < 2; ++ks) {
            int ca = ((ks * 4 + q) ^ (ml & 7)) * 8;
            s16x8 a = *(const s16x8*)&As[cur][(w * 16 + ml) * BK + ca];
            #pragma unroll
            for (int ct = 0; ct < 8; ++ct) {
                s16x8 b = *(const s16x8*)&Bs[cur][(ct * 16 + ml) * BK + ca];
                acc[ct] = __builtin_amdgcn_mfma_f32_16x16x32_bf16(a, b, acc[ct], 0, 0, 0);
            }
        }
        __builtin_amdgcn_s_setprio(0);
    }

    float c = fabsf(curv[0]);
    float sc = sqrtf(c);
    float cb[8], lb[8];
    #pragma unroll
    for (int ct = 0; ct < 8; ++ct) {
        cb[ct] = conv_b[ct * 16 + ml];
        lb[ct] = lin_b[ct * 16 + ml];
    }
    #pragma unroll
    for (int r = 0; r < 4; ++r) {
        int n = n0 + w * 16 + q * 4 + r;  // D-frag: row = quad*4 + reg, col = lane&15
        bool valid = (n < N_NODES);
        float dgf = 0.f;
        if (valid) dgf = (deg[n] > 0) ? 1.0f : 0.0f;
        float y[8];
        float ssq = 0.f;
        #pragma unroll
        for (int ct = 0; ct < 8; ++ct) {
            float v = acc[ct][r] + cb[ct] + dgf * lb[ct];
            y[ct] = v;
            ssq += v * v;
        }
        ssq += __shfl_xor(ssq, 1, 64);
        ssq += __shfl_xor(ssq, 2, 64);
        ssq += __shfl_xor(ssq, 4, 64);
        ssq += __shfl_xor(ssq, 8, 64);
        float un = fmaxf(sqrtf(ssq), 1e-15f);
        float z = sc * un;
        // os = tanh(z)/z; series for z<0.25 (err ~3e-7), libm fallback otherwise
        float os;
        if (z < 0.25f) {
            float z2 = z * z;
            os = 1.0f + z2 * (-0.33333333f + z2 * (0.13333333f - z2 * 0.053968254f));
        } else {
            os = tanhf(z) / z;
        }
        if (valid) {
            #pragma unroll
            for (int ct = 0; ct < 8; ++ct)
                out[n * DIM + ct * 16 + ml] = y[ct] * os;  // f32 output
        }
    }
}

extern "C" void kernel_launch(void* const* d_in, const int* in_sizes, int n_in,
                              void* d_out, int out_size, void* d_ws, size_t ws_size,
                              hipStream_t stream) {
    (void)in_sizes; (void)n_in; (void)out_size; (void)ws_size;
    const float* node   = (const float*)d_in[0];   // inputs f32, output f32 (confirmed R3)
    const float* h1     = (const float*)d_in[1];
    const float* h2     = (const float*)d_in[2];
    const float* h3     = (const float*)d_in[3];
    const float* lin_w  = (const float*)d_in[4];
    const float* lin_b  = (const float*)d_in[5];
    const float* conv_w = (const float*)d_in[6];
    const float* conv_b = (const float*)d_in[7];
    const float* curv   = (const float*)d_in[8];
    const int* esrc = (const int*)d_in[9];
    const int* edst = (const int*)d_in[10];
    float* out = (float*)d_out;

    // ws layout (bytes):
    //   [0, 51,249,152)           A        bf16 [50048][512] (0:128 neigh | h1t | h2t | h3t)
    //   [51,249,152, 64,049,152)  node_t   bf16 [N][128] (pre-scaled node tangent)
    //   [64,049,152, 64,180,224)  Wt       bf16 [128][512]
    //   [64,180,224, 64,380,224)  deg      i32 [N]   } adjacent for fused zero
    //   [64,380,224, 64,580,224)  cursor   i32 [N]   }
    //   [64,580,224, 64,780,224)  rowstart i32 [N]
    //   [64,780,224, 67,280,224)  csr_src  i32 [E]
    //   [67,280,224, 67,281,248)  blocksum i32 [256]
    char* ws = (char*)d_ws;
    unsigned short* A = (unsigned short*)ws;
    unsigned short* node_t = (unsigned short*)(ws + 51249152);
    unsigned short* Wt = (unsigned short*)(ws + 64049152);
    int* deg = (int*)(ws + 64180224);
    int* cursor = (int*)(ws + 64380224);
    int* rowstart = (int*)(ws + 64580224);
    int* csr_src = (int*)(ws + 64780224);
    int* blocksum = (int*)(ws + 67280224);

    hipLaunchKernelGGL(k_setup, dim3(SETUP_BLOCKS), dim3(256), 0, stream,
                       node, h1, h2, h3, lin_w, conv_w, curv, node_t, A, Wt, deg);
    hipLaunchKernelGGL(k_hist, dim3(EBLK), dim3(256), 0, stream, edst, deg);
    hipLaunchKernelGGL(k_scan1, dim3(NBLK), dim3(256), 0, stream, deg, rowstart, blocksum);
    hipLaunchKernelGGL(k_scan2, dim3(1), dim3(256), 0, stream, blocksum);
    hipLaunchKernelGGL(k_bucket, dim3(EBLK), dim3(256), 0, stream,
                       esrc, edst, rowstart, blocksum, cursor, csr_src);
    hipLaunchKernelGGL(k_gather, dim3(12500), dim3(256), 0, stream,
                       csr_src, rowstart, blocksum, deg, node_t, A);
    hipLaunchKernelGGL(k_gemm, dim3((N_NODES + RB - 1) / RB), dim3(256), 0, stream,
                       A, deg, Wt, lin_b, conv_b, curv, out);
}